// Round 1
// 1107.402 us; speedup vs baseline: 1.0333x; 1.0333x over previous
//
#include <hip/hip_runtime.h>
#include <hip/hip_bf16.h>
#include <math.h>

#define BATCH 8192
#define DDIM 256
#define HDIM 266
#define NPAD 320
#define TSTEPS 20
#define BN_EPS 1e-5f
#define LSTR 72         // LDS row stride in shorts (144 B; even bank spread for b128)

typedef __attribute__((ext_vector_type(8))) short short8;   // 8 bf16
typedef __attribute__((ext_vector_type(4))) float f32x4;

__device__ __forceinline__ short f2bf(float f) {
    __hip_bfloat16 h = __float2bfloat16(f);
    return *reinterpret_cast<short*>(&h);
}
__device__ __forceinline__ float bf2f(short s) {
    union { unsigned u; float f; } v;
    v.u = ((unsigned)(unsigned short)s) << 16;
    return v.f;
}

// ---------------------------------------------------------------------------
// Merged prep: pad+convert all weights (bf16) / biases (fp32), convert x to
// bf16, and zero the stats accumulator region — one kernel.
// ---------------------------------------------------------------------------
#define SZ_W1B (20L * 320 * 256)
#define SZ_W2B (20L * 320 * 320)
#define SZ_W3B (20L * 256 * 320)
#define SZ_VW1 (320L * 256)
#define SZ_VW2 (320L * 320)
#define SZ_B1P (20L * 320)
#define SZ_B2P (20L * 320)
#define SZ_XTB (8192L * 256)
#define ZCOUNT (4L * 21 * NPAD + 2)
#define PREP_TOTAL (SZ_W1B + SZ_W2B + SZ_W3B + SZ_VW1 + SZ_VW2 + SZ_B1P + SZ_B2P + 3 * 320 + SZ_XTB + ZCOUNT)

__global__ __launch_bounds__(256)
void prep_k(short* __restrict__ W1b, const float* __restrict__ W1,
            short* __restrict__ W2b, const float* __restrict__ W2,
            short* __restrict__ W3b, const float* __restrict__ W3,
            short* __restrict__ vW1b, const float* __restrict__ vW1,
            short* __restrict__ vW2b, const float* __restrict__ vW2,
            float* __restrict__ b1p, const float* __restrict__ b1,
            float* __restrict__ b2p, const float* __restrict__ b2,
            float* __restrict__ vb1p, const float* __restrict__ vb1,
            float* __restrict__ vb2p, const float* __restrict__ vb2,
            float* __restrict__ vW3p, const float* __restrict__ vW3,
            const float* __restrict__ x, short* __restrict__ xtb,
            float* __restrict__ zbase)
{
    long idx = (long)blockIdx.x * 256 + threadIdx.x;
    if (idx < SZ_W1B) {  // [20][320][256], src [20][266][256]
        long k = idx % 256, r = (idx / 256) % 320, t = idx / (256L * 320);
        float v = (r < HDIM) ? W1[((size_t)t * HDIM + r) * 256 + k] : 0.0f;
        W1b[idx] = f2bf(v); return;
    }
    idx -= SZ_W1B;
    if (idx < SZ_W2B) {  // [20][320][320], src [20][266][266]
        long k = idx % 320, r = (idx / 320) % 320, t = idx / (320L * 320);
        float v = (r < HDIM && k < HDIM) ? W2[((size_t)t * HDIM + r) * HDIM + k] : 0.0f;
        W2b[idx] = f2bf(v); return;
    }
    idx -= SZ_W2B;
    if (idx < SZ_W3B) {  // [20][256][320], src [20][256][266]
        long k = idx % 320, r = (idx / 320) % 256, t = idx / (320L * 256);
        float v = (k < HDIM) ? W3[((size_t)t * 256 + r) * HDIM + k] : 0.0f;
        W3b[idx] = f2bf(v); return;
    }
    idx -= SZ_W3B;
    if (idx < SZ_VW1) {  // [320][256], src [266][256]
        long k = idx % 256, r = idx / 256;
        float v = (r < HDIM) ? vW1[(size_t)r * 256 + k] : 0.0f;
        vW1b[idx] = f2bf(v); return;
    }
    idx -= SZ_VW1;
    if (idx < SZ_VW2) {  // [320][320], src [266][266]
        long k = idx % 320, r = idx / 320;
        float v = (r < HDIM && k < HDIM) ? vW2[(size_t)r * HDIM + k] : 0.0f;
        vW2b[idx] = f2bf(v); return;
    }
    idx -= SZ_VW2;
    if (idx < SZ_B1P) { long n = idx % 320, t = idx / 320;
        b1p[idx] = (n < HDIM) ? b1[(size_t)t * HDIM + n] : 0.0f; return; }
    idx -= SZ_B1P;
    if (idx < SZ_B2P) { long n = idx % 320, t = idx / 320;
        b2p[idx] = (n < HDIM) ? b2[(size_t)t * HDIM + n] : 0.0f; return; }
    idx -= SZ_B2P;
    if (idx < 320) { vb1p[idx] = (idx < HDIM) ? vb1[idx] : 0.0f; return; }
    idx -= 320;
    if (idx < 320) { vb2p[idx] = (idx < HDIM) ? vb2[idx] : 0.0f; return; }
    idx -= 320;
    if (idx < 320) { vW3p[idx] = (idx < HDIM) ? vW3[idx] : 0.0f; return; }
    idx -= 320;
    if (idx < SZ_XTB) { xtb[idx] = f2bf(x[idx]); return; }
    idx -= SZ_XTB;
    if (idx < ZCOUNT) { zbase[idx] = 0.0f; return; }
}

// ---------------------------------------------------------------------------
// GEMM1 (pure): C[B,320] = A[B,256] @ W[320,256]^T + biasp. 64x64 tile, BK=64,
// reg-prefetch. Epilogue: bf16 C + column sum/sumsq (cols < HDIM).
// gridDim.z==2 runs a second (v-net) parameter set on the same A.
// ---------------------------------------------------------------------------
__global__ __launch_bounds__(256)
void gemm1_k(const short* __restrict__ A,
             const short* __restrict__ W0a, const float* __restrict__ bias0,
             short* __restrict__ C0a, float* __restrict__ cs0, float* __restrict__ cq0,
             const short* __restrict__ W1a, const float* __restrict__ bias1,
             short* __restrict__ C1a, float* __restrict__ cs1, float* __restrict__ cq1)
{
    const short* W      = blockIdx.z ? W1a   : W0a;
    const float* biasp  = blockIdx.z ? bias1 : bias0;
    short* C            = blockIdx.z ? C1a   : C0a;
    float* csum         = blockIdx.z ? cs1   : cs0;
    float* csq          = blockIdx.z ? cq1   : cq0;

    __shared__ __align__(16) short As[64 * LSTR];
    __shared__ __align__(16) short Bs[64 * LSTR];
    const int tid = threadIdx.x;
    const int col0 = blockIdx.x * 64, row0 = blockIdx.y * 64;
    const int lane = tid & 63, w = tid >> 6, q = lane >> 4, m = lane & 15;
    const int wr = (w >> 1) * 32, wc = (w & 1) * 32;
    const int srow = tid >> 2, kq = (tid & 3) * 8;

    const short* ap = A + (size_t)(row0 + srow) * DDIM + kq;
    const short* wp = W + (size_t)(col0 + srow) * DDIM + kq;
    short8 ra0 = *(const short8*)ap;
    short8 ra1 = *(const short8*)(ap + 32);
    short8 rw0 = *(const short8*)wp;
    short8 rw1 = *(const short8*)(wp + 32);

    f32x4 acc[2][2];
    #pragma unroll
    for (int i = 0; i < 2; ++i)
        #pragma unroll
        for (int j = 0; j < 2; ++j) acc[i][j] = (f32x4){0.f, 0.f, 0.f, 0.f};

    #pragma unroll
    for (int kt = 0; kt < 4; ++kt) {
        *(short8*)&As[srow * LSTR + kq]      = ra0;
        *(short8*)&As[srow * LSTR + kq + 32] = ra1;
        *(short8*)&Bs[srow * LSTR + kq]      = rw0;
        *(short8*)&Bs[srow * LSTR + kq + 32] = rw1;
        __syncthreads();
        if (kt < 3) {
            ap += 64; wp += 64;
            ra0 = *(const short8*)ap; ra1 = *(const short8*)(ap + 32);
            rw0 = *(const short8*)wp; rw1 = *(const short8*)(wp + 32);
        }
        #pragma unroll
        for (int kk = 0; kk < 2; ++kk) {
            short8 fa0 = *(const short8*)&As[(wr + m)      * LSTR + kk * 32 + q * 8];
            short8 fa1 = *(const short8*)&As[(wr + 16 + m) * LSTR + kk * 32 + q * 8];
            short8 fb0 = *(const short8*)&Bs[(wc + m)      * LSTR + kk * 32 + q * 8];
            short8 fb1 = *(const short8*)&Bs[(wc + 16 + m) * LSTR + kk * 32 + q * 8];
            acc[0][0] = __builtin_amdgcn_mfma_f32_16x16x32_bf16(fa0, fb0, acc[0][0], 0, 0, 0);
            acc[0][1] = __builtin_amdgcn_mfma_f32_16x16x32_bf16(fa0, fb1, acc[0][1], 0, 0, 0);
            acc[1][0] = __builtin_amdgcn_mfma_f32_16x16x32_bf16(fa1, fb0, acc[1][0], 0, 0, 0);
            acc[1][1] = __builtin_amdgcn_mfma_f32_16x16x32_bf16(fa1, fb1, acc[1][1], 0, 0, 0);
        }
        __syncthreads();
    }

    float cs[2], cq[2];
    #pragma unroll
    for (int j = 0; j < 2; ++j) {
        const int col = col0 + wc + j * 16 + m;
        const float bv = biasp[col];
        float s = 0.0f, sq = 0.0f;
        #pragma unroll
        for (int i = 0; i < 2; ++i)
            #pragma unroll
            for (int r = 0; r < 4; ++r) {
                float v = acc[i][j][r] + bv;
                int row = row0 + wr + i * 16 + q * 4 + r;
                C[(size_t)row * NPAD + col] = f2bf(v);
                s += v; sq += v * v;
            }
        cs[j] = s; cq[j] = sq;
    }
    #pragma unroll
    for (int j = 0; j < 2; ++j) {
        cs[j] += __shfl_xor(cs[j], 16); cs[j] += __shfl_xor(cs[j], 32);
        cq[j] += __shfl_xor(cq[j], 16); cq[j] += __shfl_xor(cq[j], 32);
    }
    float* reds = (float*)As;
    float* redq = (float*)Bs;
    if (q == 0) {
        #pragma unroll
        for (int j = 0; j < 2; ++j) {
            reds[(w >> 1) * 64 + wc + j * 16 + m] = cs[j];
            redq[(w >> 1) * 64 + wc + j * 16 + m] = cq[j];
        }
    }
    __syncthreads();
    if (tid < 64) {
        int col = col0 + tid;
        if (col < HDIM) {
            atomicAdd(&csum[col], reds[tid] + reds[64 + tid]);
            atomicAdd(&csq[col],  redq[tid] + redq[64 + tid]);
        }
    }
}

// ---------------------------------------------------------------------------
// GEMM2 (BN-staged A): C[B,320] = bnrelu(A)[B,320] @ W[320,320]^T + biasp.
// 32x160 tile, BK=64, reg-prefetch. gridDim.z==2 runs second (v-net) set.
// ---------------------------------------------------------------------------
__global__ __launch_bounds__(256)
void gemm2_k(const short* __restrict__ A0a, const short* __restrict__ W0a,
             const float* __restrict__ bias0,
             const float* __restrict__ csi0, const float* __restrict__ cqi0,
             const float* __restrict__ g0a, const float* __restrict__ be0a,
             short* __restrict__ C0a, float* __restrict__ cso0, float* __restrict__ cqo0,
             const short* __restrict__ A1a, const short* __restrict__ W1a,
             const float* __restrict__ bias1,
             const float* __restrict__ csi1, const float* __restrict__ cqi1,
             const float* __restrict__ g1a, const float* __restrict__ be1a,
             short* __restrict__ C1a, float* __restrict__ cso1, float* __restrict__ cqo1)
{
    const short* A       = blockIdx.z ? A1a   : A0a;
    const short* W       = blockIdx.z ? W1a   : W0a;
    const float* biasp   = blockIdx.z ? bias1 : bias0;
    const float* csum_in = blockIdx.z ? csi1  : csi0;
    const float* csq_in  = blockIdx.z ? cqi1  : cqi0;
    const float* g       = blockIdx.z ? g1a   : g0a;
    const float* be      = blockIdx.z ? be1a  : be0a;
    short* C             = blockIdx.z ? C1a   : C0a;
    float* csum_out      = blockIdx.z ? cso1  : cso0;
    float* csq_out       = blockIdx.z ? cqo1  : cqo0;

    __shared__ __align__(16) short As[32 * LSTR];
    __shared__ __align__(16) short Bs[160 * LSTR];
    __shared__ float sS[NPAD], sT[NPAD];
    const int tid = threadIdx.x;
    for (int k = tid; k < NPAD; k += 256) {
        float s = 0.0f, t = 0.0f;
        if (k < HDIM) {
            float mn = csum_in[k] * (1.0f / BATCH);
            float vr = csq_in[k] * (1.0f / BATCH) - mn * mn;
            float rs = rsqrtf(fmaxf(vr, 0.0f) + BN_EPS);
            s = g[k] * rs;
            t = be[k] - mn * s;
        }
        sS[k] = s; sT[k] = t;
    }
    __syncthreads();

    const int col0 = blockIdx.x * 160, row0 = blockIdx.y * 32;
    const int lane = tid & 63, w = tid >> 6, q = lane >> 4, m = lane & 15;
    const int rh = w >> 1, ch = w & 1;
    const int srowA = tid >> 3, kqA = (tid & 7) * 8;

    const short* ap = A + (size_t)(row0 + srowA) * NPAD + kqA;
    short8 rA = *(const short8*)ap;
    short8 rB[5];
    #pragma unroll
    for (int i = 0; i < 5; ++i) {
        int s = tid + 256 * i;
        rB[i] = *(const short8*)(W + (size_t)(col0 + (s >> 3)) * NPAD + ((s & 7) * 8));
    }

    f32x4 acc[5];
    #pragma unroll
    for (int j = 0; j < 5; ++j) acc[j] = (f32x4){0.f, 0.f, 0.f, 0.f};

    #pragma unroll
    for (int kt = 0; kt < 5; ++kt) {
        short8 ta;
        const int kb = kt * 64 + kqA;
        #pragma unroll
        for (int j = 0; j < 8; ++j) {
            float f = bf2f(rA[j]);
            f = fmaxf(f * sS[kb + j] + sT[kb + j], 0.0f);
            ta[j] = f2bf(f);
        }
        *(short8*)&As[srowA * LSTR + kqA] = ta;
        #pragma unroll
        for (int i = 0; i < 5; ++i) {
            int s = tid + 256 * i;
            *(short8*)&Bs[(s >> 3) * LSTR + (s & 7) * 8] = rB[i];
        }
        __syncthreads();
        if (kt < 4) {
            ap += 64;
            rA = *(const short8*)ap;
            #pragma unroll
            for (int i = 0; i < 5; ++i) {
                int s = tid + 256 * i;
                rB[i] = *(const short8*)(W + (size_t)(col0 + (s >> 3)) * NPAD
                                         + (kt + 1) * 64 + ((s & 7) * 8));
            }
        }
        #pragma unroll
        for (int kk = 0; kk < 2; ++kk) {
            short8 fa = *(const short8*)&As[(rh * 16 + m) * LSTR + kk * 32 + q * 8];
            #pragma unroll
            for (int j = 0; j < 5; ++j) {
                short8 fb = *(const short8*)&Bs[(ch * 80 + j * 16 + m) * LSTR + kk * 32 + q * 8];
                acc[j] = __builtin_amdgcn_mfma_f32_16x16x32_bf16(fa, fb, acc[j], 0, 0, 0);
            }
        }
        __syncthreads();
    }

    float csv[5], cqv[5];
    #pragma unroll
    for (int j = 0; j < 5; ++j) {
        const int col = col0 + ch * 80 + j * 16 + m;
        const float bv = biasp[col];
        float s = 0.0f, sq = 0.0f;
        #pragma unroll
        for (int r = 0; r < 4; ++r) {
            float v = acc[j][r] + bv;
            int row = row0 + rh * 16 + q * 4 + r;
            C[(size_t)row * NPAD + col] = f2bf(v);
            s += v; sq += v * v;
        }
        csv[j] = s; cqv[j] = sq;
    }
    #pragma unroll
    for (int j = 0; j < 5; ++j) {
        csv[j] += __shfl_xor(csv[j], 16); csv[j] += __shfl_xor(csv[j], 32);
        cqv[j] += __shfl_xor(cqv[j], 16); cqv[j] += __shfl_xor(cqv[j], 32);
    }
    float* redS = (float*)As;          // 640 floats needed; As = 4608 B
    float* redQ = redS + 320;
    if (q == 0) {
        #pragma unroll
        for (int j = 0; j < 5; ++j) {
            redS[rh * 160 + ch * 80 + j * 16 + m] = csv[j];
            redQ[rh * 160 + ch * 80 + j * 16 + m] = cqv[j];
        }
    }
    __syncthreads();
    if (tid < 160) {
        int col = col0 + tid;
        if (col < HDIM) {
            atomicAdd(&csum_out[col], redS[tid] + redS[160 + tid]);
            atomicAdd(&csq_out[col],  redQ[tid] + redQ[160 + tid]);
        }
    }
}

// ---------------------------------------------------------------------------
// g31_k: fused gemm3(t) + SDE xt-update + gemm1(t+1).
// Phase 1: grad[32,256] = bnrelu(hp2 rows) @ W3^T + b3 (full-width row slab).
// Epilogue: update xt (global bf16 + LDS copy), row-local f/dot (plain store).
// Phase 2: hp1' = xt'(LDS) @ W1(t+1)^T + b1(t+1), + column stats for BN1.
// 512 threads (8 waves: rh=w>>2 row-half, ch=w&3 col-quarter), 256 blocks.
// gridDim.z==2: z==1 blocks run the v-net row-dot (vrow) instead (t==0 only).
// ---------------------------------------------------------------------------
__global__ __launch_bounds__(512)
void g31_k(const short* __restrict__ A,       // hp2
           const short* __restrict__ W3t, const float* __restrict__ b3t,
           const float* __restrict__ csum_in, const float* __restrict__ csq_in,
           const float* __restrict__ g, const float* __restrict__ be,
           const float* __restrict__ xi_t,
           short* __restrict__ xtb, float* __restrict__ xout,
           float* __restrict__ ftab_t, float* __restrict__ dtab_t,
           const float* __restrict__ tg, int t, int last,
           const short* __restrict__ W1n, const float* __restrict__ b1n,
           short* __restrict__ hp1, float* __restrict__ csn, float* __restrict__ cqn,
           const short* __restrict__ Av, const float* __restrict__ csV, const float* __restrict__ cqV,
           const float* __restrict__ vg, const float* __restrict__ vbe,
           const float* __restrict__ vW3p, const float* __restrict__ vb3,
           float* __restrict__ pre3, float* __restrict__ s3, float* __restrict__ q3)
{
    __shared__ __align__(16) short As1[32 * LSTR];       // phase-1 A (bnrelu hp2)
    __shared__ __align__(16) short As2[128 * LSTR];      // xt' staged for phase 2
    __shared__ __align__(16) short Bs[320 * LSTR];       // W3 chunk / W1 chunk
    __shared__ float sS[NPAD], sT[NPAD];
    __shared__ float redF[128], redD[128];
    __shared__ float redS[2 * NPAD], redQ[2 * NPAD];

    const int tid = threadIdx.x;
    const int row0 = blockIdx.x * 32;

    if (blockIdx.z == 1) {
        // ---- v-net layer-3 row dot (vrow), 32 rows per block ----
        for (int k = tid; k < NPAD; k += 512) {
            float s = 0.0f, tt = 0.0f;
            if (k < HDIM) {
                float mn = csV[k] * (1.0f / BATCH);
                float vr = cqV[k] * (1.0f / BATCH) - mn * mn;
                float rs = rsqrtf(fmaxf(vr, 0.0f) + BN_EPS);
                s = vg[k] * rs;
                tt = vbe[k] - mn * s;
            }
            sS[k] = s; sT[k] = tt;
        }
        __syncthreads();
        const int wv = tid >> 6, lane = tid & 63;
        float ps = 0.0f, pq = 0.0f;
        #pragma unroll
        for (int r4 = 0; r4 < 4; ++r4) {
            int row = row0 + wv * 4 + r4;
            float sum = 0.0f;
            #pragma unroll
            for (int c = 0; c < 5; ++c) {
                int k = c * 64 + lane;
                float v = fmaxf(bf2f(Av[(size_t)row * NPAD + k]) * sS[k] + sT[k], 0.0f);
                sum += v * vW3p[k];
            }
            sum += __shfl_xor(sum, 1);  sum += __shfl_xor(sum, 2);
            sum += __shfl_xor(sum, 4);  sum += __shfl_xor(sum, 8);
            sum += __shfl_xor(sum, 16); sum += __shfl_xor(sum, 32);
            if (lane == 0) {
                float p = sum + vb3[0];
                pre3[row] = p;
                ps += p; pq += p * p;
            }
        }
        if (lane == 0) { redF[wv] = ps; redD[wv] = pq; }
        __syncthreads();
        if (tid == 0) {
            float a = 0.0f, b = 0.0f;
            #pragma unroll
            for (int i = 0; i < 8; ++i) { a += redF[i]; b += redD[i]; }
            atomicAdd(s3, a); atomicAdd(q3, b);
        }
        return;
    }

    // ---- BN2 scale/shift ----
    for (int k = tid; k < NPAD; k += 512) {
        float s = 0.0f, tt = 0.0f;
        if (k < HDIM) {
            float mn = csum_in[k] * (1.0f / BATCH);
            float vr = csq_in[k] * (1.0f / BATCH) - mn * mn;
            float rs = rsqrtf(fmaxf(vr, 0.0f) + BN_EPS);
            s = g[k] * rs;
            tt = be[k] - mn * s;
        }
        sS[k] = s; sT[k] = tt;
    }
    __syncthreads();

    const int lane = tid & 63, w = tid >> 6, q = lane >> 4, m = lane & 15;
    const int rh = w >> 2, ch = w & 3;
    const int srowA = tid >> 3, kqA = (tid & 7) * 8;   // A-staging: tid<256 only

    const short* ap = A + (size_t)(row0 + srowA) * NPAD + kqA;
    short8 rA;
    if (tid < 256) rA = *(const short8*)ap;
    short8 rB[4];
    #pragma unroll
    for (int i = 0; i < 4; ++i) {
        int s = tid + 512 * i;
        rB[i] = *(const short8*)(W3t + (size_t)(s >> 3) * NPAD + ((s & 7) * 8));
    }

    f32x4 acc[4];
    #pragma unroll
    for (int j = 0; j < 4; ++j) acc[j] = (f32x4){0.f, 0.f, 0.f, 0.f};

    // ---- phase 1: grad = bnrelu(hp2) @ W3^T ----
    #pragma unroll
    for (int kt = 0; kt < 5; ++kt) {
        if (tid < 256) {
            short8 ta;
            const int kb = kt * 64 + kqA;
            #pragma unroll
            for (int j = 0; j < 8; ++j) {
                float f = bf2f(rA[j]);
                f = fmaxf(f * sS[kb + j] + sT[kb + j], 0.0f);
                ta[j] = f2bf(f);
            }
            *(short8*)&As1[srowA * LSTR + kqA] = ta;
        }
        #pragma unroll
        for (int i = 0; i < 4; ++i) {
            int s = tid + 512 * i;
            *(short8*)&Bs[(s >> 3) * LSTR + (s & 7) * 8] = rB[i];
        }
        __syncthreads();
        if (kt < 4) {
            ap += 64;
            if (tid < 256) rA = *(const short8*)ap;
            #pragma unroll
            for (int i = 0; i < 4; ++i) {
                int s = tid + 512 * i;
                rB[i] = *(const short8*)(W3t + (size_t)(s >> 3) * NPAD
                                         + (kt + 1) * 64 + ((s & 7) * 8));
            }
        }
        #pragma unroll
        for (int kk = 0; kk < 2; ++kk) {
            short8 fa = *(const short8*)&As1[(rh * 16 + m) * LSTR + kk * 32 + q * 8];
            #pragma unroll
            for (int j = 0; j < 4; ++j) {
                short8 fb = *(const short8*)&Bs[(ch * 64 + j * 16 + m) * LSTR + kk * 32 + q * 8];
                acc[j] = __builtin_amdgcn_mfma_f32_16x16x32_bf16(fa, fb, acc[j], 0, 0, 0);
            }
        }
        __syncthreads();
    }

    // prefetch W1(t+1) chunk 0 so HBM latency hides under the epilogue
    short8 rW[5];
    if (!last) {
        #pragma unroll
        for (int i = 0; i < 5; ++i) {
            int s = tid + 512 * i;
            rW[i] = *(const short8*)(W1n + (size_t)(s >> 3) * DDIM + ((s & 7) * 8));
        }
    }

    // ---- SDE epilogue (LAMBDA=1, SIGMA=1) ----
    const float ht = tg[t + 1] - tg[t];
    const float sn = sqrtf(ht);
    float fr[4] = {0.f, 0.f, 0.f, 0.f};
    float dr[4] = {0.f, 0.f, 0.f, 0.f};
    #pragma unroll
    for (int j = 0; j < 4; ++j) {
        const int col = ch * 64 + j * 16 + m;
        const float bv = b3t[col];
        #pragma unroll
        for (int r = 0; r < 4; ++r) {
            const int lr = rh * 16 + q * 4 + r;
            const size_t idx = (size_t)(row0 + lr) * DDIM + col;
            float grad = acc[j][r] + bv;
            float noise = sn * xi_t[idx];
            float nx = bf2f(xtb[idx]) - grad * ht + noise;
            xtb[idx] = f2bf(nx);
            if (last) xout[idx] = nx;
            else      As2[(ch * 32 + lr) * LSTR + (j * 16 + m)] = f2bf(nx);
            fr[r] += grad * grad;
            dr[r] += grad * noise;
        }
    }
    #pragma unroll
    for (int r = 0; r < 4; ++r) {
        fr[r] += __shfl_xor(fr[r], 1); dr[r] += __shfl_xor(dr[r], 1);
        fr[r] += __shfl_xor(fr[r], 2); dr[r] += __shfl_xor(dr[r], 2);
        fr[r] += __shfl_xor(fr[r], 4); dr[r] += __shfl_xor(dr[r], 4);
        fr[r] += __shfl_xor(fr[r], 8); dr[r] += __shfl_xor(dr[r], 8);
    }
    if (m == 0) {
        #pragma unroll
        for (int r = 0; r < 4; ++r) {
            redF[ch * 32 + rh * 16 + q * 4 + r] = fr[r];
            redD[ch * 32 + rh * 16 + q * 4 + r] = dr[r];
        }
    }
    __syncthreads();
    if (tid < 32) {   // block owns full rows -> plain stores, no atomics
        ftab_t[row0 + tid] = redF[tid] + redF[32 + tid] + redF[64 + tid] + redF[96 + tid];
        dtab_t[row0 + tid] = redD[tid] + redD[32 + tid] + redD[64 + tid] + redD[96 + tid];
    }
    if (last) return;

    // ---- phase 2: hp1' = xt'(LDS) @ W1(t+1)^T + b1(t+1) ----
    f32x4 acc2[5];
    #pragma unroll
    for (int j = 0; j < 5; ++j) acc2[j] = (f32x4){0.f, 0.f, 0.f, 0.f};

    #pragma unroll
    for (int kt = 0; kt < 4; ++kt) {
        #pragma unroll
        for (int i = 0; i < 5; ++i) {
            int s = tid + 512 * i;
            *(short8*)&Bs[(s >> 3) * LSTR + (s & 7) * 8] = rW[i];
        }
        __syncthreads();
        if (kt < 3) {
            #pragma unroll
            for (int i = 0; i < 5; ++i) {
                int s = tid + 512 * i;
                rW[i] = *(const short8*)(W1n + (size_t)(s >> 3) * DDIM
                                         + (kt + 1) * 64 + ((s & 7) * 8));
            }
        }
        #pragma unroll
        for (int kk = 0; kk < 2; ++kk) {
            short8 fa = *(const short8*)&As2[(kt * 32 + rh * 16 + m) * LSTR + kk * 32 + q * 8];
            #pragma unroll
            for (int j = 0; j < 5; ++j) {
                short8 fb = *(const short8*)&Bs[(ch * 80 + j * 16 + m) * LSTR + kk * 32 + q * 8];
                acc2[j] = __builtin_amdgcn_mfma_f32_16x16x32_bf16(fa, fb, acc2[j], 0, 0, 0);
            }
        }
        __syncthreads();
    }

    float csv[5], cqv[5];
    #pragma unroll
    for (int j = 0; j < 5; ++j) {
        const int col = ch * 80 + j * 16 + m;
        const float bv = b1n[col];
        float s = 0.0f, sq = 0.0f;
        #pragma unroll
        for (int r = 0; r < 4; ++r) {
            float v = acc2[j][r] + bv;
            int row = row0 + rh * 16 + q * 4 + r;
            hp1[(size_t)row * NPAD + col] = f2bf(v);
            s += v; sq += v * v;
        }
        csv[j] = s; cqv[j] = sq;
    }
    #pragma unroll
    for (int j = 0; j < 5; ++j) {
        csv[j] += __shfl_xor(csv[j], 16); csv[j] += __shfl_xor(csv[j], 32);
        cqv[j] += __shfl_xor(cqv[j], 16); cqv[j] += __shfl_xor(cqv[j], 32);
    }
    if (q == 0) {
        #pragma unroll
        for (int j = 0; j < 5; ++j) {
            redS[rh * NPAD + ch * 80 + j * 16 + m] = csv[j];
            redQ[rh * NPAD + ch * 80 + j * 16 + m] = cqv[j];
        }
    }
    __syncthreads();
    if (tid < HDIM) {
        atomicAdd(&csn[tid], redS[tid] + redS[NPAD + tid]);
        atomicAdd(&cqn[tid], redQ[tid] + redQ[NPAD + tid]);
    }
}

// final: vT[i] = relu(BN(pre3))[i] + sum_t (dot_t[i] - f_t[i]*ht_t)  (v3b folded in)
__global__ __launch_bounds__(256)
void final_v_k(const float* __restrict__ pre3,
               const float* __restrict__ s3, const float* __restrict__ q3,
               const float* __restrict__ vg3, const float* __restrict__ vbe3,
               const float* __restrict__ ftab, const float* __restrict__ dtab,
               const float* __restrict__ tg, float* __restrict__ outv)
{
    int i = blockIdx.x * 256 + threadIdx.x;
    if (i >= BATCH) return;
    float mn = s3[0] * (1.0f / BATCH);
    float va = fmaxf(q3[0] * (1.0f / BATCH) - mn * mn, 0.0f);
    float rs = rsqrtf(va + BN_EPS);
    float v = fmaxf(vg3[0] * (pre3[i] - mn) * rs + vbe3[0], 0.0f);
    for (int t = 0; t < TSTEPS; ++t) {
        float ht = tg[t + 1] - tg[t];
        v += dtab[(size_t)t * BATCH + i] - ftab[(size_t)t * BATCH + i] * ht;
    }
    outv[i] = v;
}

extern "C" void kernel_launch(void* const* d_in, const int* in_sizes, int n_in,
                              void* d_out, int out_size, void* d_ws, size_t ws_size,
                              hipStream_t stream)
{
    const float* x    = (const float*)d_in[0];
    const float* xi   = (const float*)d_in[1];
    const float* tg   = (const float*)d_in[2];
    const float* W1   = (const float*)d_in[3];
    const float* b1   = (const float*)d_in[4];
    const float* g1   = (const float*)d_in[5];
    const float* be1  = (const float*)d_in[6];
    const float* W2   = (const float*)d_in[7];
    const float* b2   = (const float*)d_in[8];
    const float* g2   = (const float*)d_in[9];
    const float* be2  = (const float*)d_in[10];
    const float* W3   = (const float*)d_in[11];
    const float* b3   = (const float*)d_in[12];
    const float* vW1  = (const float*)d_in[13];
    const float* vb1  = (const float*)d_in[14];
    const float* vg1  = (const float*)d_in[15];
    const float* vbe1 = (const float*)d_in[16];
    const float* vW2  = (const float*)d_in[17];
    const float* vb2  = (const float*)d_in[18];
    const float* vg2  = (const float*)d_in[19];
    const float* vbe2 = (const float*)d_in[20];
    const float* vW3  = (const float*)d_in[21];
    const float* vb3  = (const float*)d_in[22];
    const float* vg3  = (const float*)d_in[23];
    const float* vbe3 = (const float*)d_in[24];

    float* out  = (float*)d_out;       // [0,B): vT ; [B, B+B*D): xT (fp32)
    float* xout = out + BATCH;

    // ---- workspace layout (bf16 region first, then fp32) ----
    short* xtb  = (short*)d_ws;                          // B*256
    short* hp1  = xtb + (size_t)BATCH * DDIM;            // B*320
    short* hp2  = hp1 + (size_t)BATCH * NPAD;            // B*320
    short* hp1v = hp2 + (size_t)BATCH * NPAD;            // B*320 (v-net)
    short* hp2v = hp1v + (size_t)BATCH * NPAD;           // B*320 (v-net)
    short* W1b  = hp2v + (size_t)BATCH * NPAD;           // SZ_W1B
    short* W2b  = W1b + SZ_W1B;
    short* W3b  = W2b + SZ_W2B;
    short* vW1b = W3b + SZ_W3B;
    short* vW2b = vW1b + SZ_VW1;
    float* fbase = (float*)(vW2b + SZ_VW2);
    float* b1p  = fbase;                       // 20*320
    float* b2p  = b1p + TSTEPS * NPAD;         // 20*320
    float* vb1p = b2p + TSTEPS * NPAD;         // 320
    float* vb2p = vb1p + NPAD;                 // 320
    float* vW3p = vb2p + NPAD;                 // 320
    float* pre3 = vW3p + NPAD;                 // B
    float* ftab = pre3 + BATCH;                // 20*B (fully overwritten each iter)
    float* dtab = ftab + (size_t)TSTEPS * BATCH;
    float* csA  = dtab + (size_t)TSTEPS * BATCH;   // zero region: 4*21*NPAD + 2
    float* cqA  = csA + 21 * NPAD;
    float* csB  = cqA + 21 * NPAD;
    float* cqB  = csB + 21 * NPAD;
    float* s3   = cqB + 21 * NPAD;
    float* q3   = s3 + 1;

    float* csV1 = csA + 20 * NPAD; float* cqV1 = cqA + 20 * NPAD;
    float* csV2 = csB + 20 * NPAD; float* cqV2 = cqB + 20 * NPAD;

    dim3 blk(256), blk5(512);

    prep_k<<<dim3((int)((PREP_TOTAL + 255) / 256)), blk, 0, stream>>>(
        W1b, W1, W2b, W2, W3b, W3, vW1b, vW1, vW2b, vW2,
        b1p, b1, b2p, b2, vb1p, vb1, vb2p, vb2, vW3p, vW3,
        x, xtb, csA);

    // step-0 layer1 + v-net layer1 in one launch (z doubles the grid)
    gemm1_k<<<dim3(5, BATCH / 64, 2), blk, 0, stream>>>(
        xtb, W1b, b1p, hp1, csA, cqA,
        vW1b, vb1p, hp1v, csV1, cqV1);
    // step-0 layer2 + v-net layer2
    gemm2_k<<<dim3(2, BATCH / 32, 2), blk, 0, stream>>>(
        hp1, W2b, b2p, csA, cqA, g1, be1, hp2, csB, cqB,
        hp1v, vW2b, vb2p, csV1, cqV1, vg1, vbe1, hp2v, csV2, cqV2);

    for (int t = 0; t < TSTEPS; ++t) {
        if (t > 0)
            gemm2_k<<<dim3(2, BATCH / 32, 1), blk, 0, stream>>>(
                hp1, W2b + (size_t)t * NPAD * NPAD, b2p + t * NPAD,
                csA + t * NPAD, cqA + t * NPAD, g1 + t * HDIM, be1 + t * HDIM,
                hp2, csB + t * NPAD, cqB + t * NPAD,
                nullptr, nullptr, nullptr, nullptr, nullptr,
                nullptr, nullptr, nullptr, nullptr, nullptr);
        const int last = (t == TSTEPS - 1) ? 1 : 0;
        const int tn = last ? 0 : t + 1;   // clamped; unused when last
        g31_k<<<dim3(BATCH / 32, 1, (t == 0) ? 2 : 1), blk5, 0, stream>>>(
            hp2, W3b + (size_t)t * DDIM * NPAD, b3 + t * DDIM,
            csB + t * NPAD, cqB + t * NPAD, g2 + t * HDIM, be2 + t * HDIM,
            xi + (size_t)t * BATCH * DDIM, xtb, xout,
            ftab + (size_t)t * BATCH, dtab + (size_t)t * BATCH,
            tg, t, last,
            W1b + (size_t)tn * NPAD * DDIM, b1p + tn * NPAD,
            hp1, csA + tn * NPAD, cqA + tn * NPAD,
            hp2v, csV2, cqV2, vg2, vbe2, vW3p, vb3, pre3, s3, q3);
    }

    final_v_k<<<dim3(BATCH / 256), blk, 0, stream>>>(
        pre3, s3, q3, vg3, vbe3, ftab, dtab, tg, out);
}